// Round 1
// baseline (616.406 us; speedup 1.0000x reference)
//
#include <hip/hip_runtime.h>
#include <math.h>

#define Bv 8
#define Tv 32
#define Nv 500
#define Fin 64
#define Hv 128
#define Ev 8000
#define Kv 3
#define BT (Bv*Tv)      /* 256 */
#define ROWS (BT*Nv)    /* 128000 */
#define TP (Tv+2)       /* 34 padded time steps */

__device__ __forceinline__ float gelu_exact(float v){
    return 0.5f*v*(1.0f + erff(v*0.70710678118654752440f));
}

// ---- graph prep: weighted degree (incl. self loop) + per-dst edge counts ----
__global__ void k_graph(const int* ei, const float* ew, float* deg, int* counts){
    int idx = blockIdx.x*256 + threadIdx.x;
    if (idx < Ev){
        int d = ei[Ev + idx];
        atomicAdd(&deg[d], ew[idx]);
        atomicAdd(&counts[d], 1);
    } else if (idx < Ev + Nv){
        atomicAdd(&deg[idx - Ev], 1.0f);   // self loop weight 1
    }
}

// ---- dinv + exclusive scan of counts -> CSR offsets (N=500 fits one block) ----
__global__ void k_scan(const float* deg, const int* counts, float* dinv, int* offs, int* cursor){
    __shared__ int sa[512], sb[512];
    int tid = threadIdx.x;
    int c = (tid < Nv) ? counts[tid] : 0;
    if (tid < Nv){
        float d = deg[tid];
        dinv[tid] = (d > 0.f) ? rsqrtf(d) : 0.f;
    }
    sa[tid] = c; __syncthreads();
    int* s = sa; int* t = sb;
    for (int off = 1; off < 512; off <<= 1){
        int v = s[tid];
        if (tid >= off) v += s[tid - off];
        t[tid] = v; __syncthreads();
        int* tmp = s; s = t; t = tmp;
    }
    int excl = s[tid] - c;
    if (tid < Nv){ offs[tid] = excl; cursor[tid] = excl; }
    if (tid == 0) offs[Nv] = Ev;
}

// ---- fill CSR (src id + normalized weight dinv[src]*ew*dinv[dst]) ----
__global__ void k_fill(const int* ei, const float* ew, const float* dinv,
                       int* cursor, int* csrc, float* cw){
    int e = blockIdx.x*256 + threadIdx.x;
    if (e >= Ev) return;
    int s = ei[e], d = ei[Ev + e];
    int pos = atomicAdd(&cursor[d], 1);
    csrc[pos] = s;
    cw[pos] = dinv[s]*ew[e]*dinv[d];
}

// ---- transpose W_temp (O,I,K) -> Wt[k][i][o] for coalesced conv loads ----
__global__ void k_wt(const float* W, float* Wt){
    int idx = blockIdx.x*256 + threadIdx.x;
    if (idx >= Hv*Hv*Kv) return;
    int o = idx/(Hv*Kv);
    int rem = idx - o*(Hv*Kv);
    int i = rem/Kv, k = rem - i*Kv;
    Wt[(k*Hv + i)*Hv + o] = W[idx];
}

// ---- fused input GEMMs: xf = x@Wg (to ws), res = x@Wr + br (to d_out) ----
// block = 1 wave; each lane owns columns h and h+64 of both outputs; 16 rows/block
__global__ __launch_bounds__(64) void k_gemm_in(const float* __restrict__ x,
        const float* __restrict__ Wg, const float* __restrict__ Wr,
        const float* __restrict__ br, float* __restrict__ xf, float* __restrict__ outres){
    __shared__ float xs[16*64];
    int lane = threadIdx.x;
    int row0 = blockIdx.x * 16;
    const float* xp = x + row0*Fin;
    for (int j = lane; j < 16*64; j += 64) xs[j] = xp[j];
    __syncthreads();
    int h0 = lane, h1 = lane + 64;
    float a0[16], a1[16], r0[16], r1[16];
    #pragma unroll
    for (int r = 0; r < 16; ++r){ a0[r]=0.f; a1[r]=0.f; r0[r]=0.f; r1[r]=0.f; }
    for (int k4 = 0; k4 < 16; ++k4){
        float wg0[4], wg1[4], wr0[4], wr1[4];
        #pragma unroll
        for (int q = 0; q < 4; ++q){
            int k = 4*k4 + q;
            wg0[q] = Wg[k*Hv + h0]; wg1[q] = Wg[k*Hv + h1];
            wr0[q] = Wr[k*Hv + h0]; wr1[q] = Wr[k*Hv + h1];
        }
        #pragma unroll
        for (int r = 0; r < 16; ++r){
            float4 xq = *(const float4*)&xs[r*64 + 4*k4];
            a0[r]=fmaf(xq.x,wg0[0],a0[r]); a0[r]=fmaf(xq.y,wg0[1],a0[r]);
            a0[r]=fmaf(xq.z,wg0[2],a0[r]); a0[r]=fmaf(xq.w,wg0[3],a0[r]);
            a1[r]=fmaf(xq.x,wg1[0],a1[r]); a1[r]=fmaf(xq.y,wg1[1],a1[r]);
            a1[r]=fmaf(xq.z,wg1[2],a1[r]); a1[r]=fmaf(xq.w,wg1[3],a1[r]);
            r0[r]=fmaf(xq.x,wr0[0],r0[r]); r0[r]=fmaf(xq.y,wr0[1],r0[r]);
            r0[r]=fmaf(xq.z,wr0[2],r0[r]); r0[r]=fmaf(xq.w,wr0[3],r0[r]);
            r1[r]=fmaf(xq.x,wr1[0],r1[r]); r1[r]=fmaf(xq.y,wr1[1],r1[r]);
            r1[r]=fmaf(xq.z,wr1[2],r1[r]); r1[r]=fmaf(xq.w,wr1[3],r1[r]);
        }
    }
    float b0 = br[h0], b1 = br[h1];
    #pragma unroll
    for (int r = 0; r < 16; ++r){
        int rr = (row0 + r)*Hv;
        xf[rr + h0] = a0[r]; xf[rr + h1] = a1[r];
        outres[rr + h0] = r0[r] + b0; outres[rr + h1] = r1[r] + b1;
    }
}

// ---- zero the t=0 / t=TP-1 pad planes of hgp ----
__global__ void k_pad(float* hgp){
    int idx = blockIdx.x*256 + threadIdx.x;
    if (idx >= Bv*Nv*2*Hv) return;
    int h  = idx & 127;
    int r  = (idx >> 7) & 1;
    int bn = idx >> 8;
    hgp[(bn*TP + r*(TP-1))*Hv + h] = 0.f;
}

// ---- GCN aggregate (gather over CSR) + bias + exact GELU -> hgp (b,n,tpad,h) ----
__global__ __launch_bounds__(128) void k_gather(const float* __restrict__ xf,
        const float* __restrict__ dinv, const int* __restrict__ offs,
        const int* __restrict__ csrc, const float* __restrict__ cw,
        const float* __restrict__ bg, float* __restrict__ hgp){
    int bid = blockIdx.x;
    int h = threadIdx.x;
    int bt = bid / Nv;          // consecutive blocks share bt -> xf slice hot in L2
    int n = bid - bt*Nv;
    int b = bt >> 5, t = bt & 31;
    const float* xb = xf + bt*Nv*Hv;
    float dv = dinv[n];
    float acc = dv*dv*xb[n*Hv + h];            // self loop
    int e0 = offs[n], e1 = offs[n+1];
    for (int e = e0; e < e1; ++e)
        acc = fmaf(cw[e], xb[csrc[e]*Hv + h], acc);
    float v = acc + bg[h];
    hgp[((b*Nv + n)*TP + (t + 1))*Hv + h] = gelu_exact(v);
}

// ---- temporal conv K=3 + bias + GELU + add residual (in d_out), write d_out ----
// one wave per (b,n); LDS holds the 34x128 window transposed [i][t] (stride 36);
// each lane owns channels o and o+64, acc[32] over t in registers.
__global__ __launch_bounds__(64) void k_conv(const float* __restrict__ hgp,
        const float* __restrict__ Wt, const float* __restrict__ btm,
        float* __restrict__ out){
    __shared__ float lh[Hv*36];
    int lane = threadIdx.x;
    int bid = blockIdx.x;
    int b = bid / Nv, n = bid - b*Nv;
    const float* hp = hgp + (b*Nv + n)*TP*Hv;
    for (int j = lane; j < TP*Hv; j += 64){
        int tp = j >> 7, i = j & 127;
        lh[i*36 + tp] = hp[j];
    }
    __syncthreads();
    int o0 = lane, o1 = lane + 64;
    float acc0[32], acc1[32];
    #pragma unroll
    for (int t = 0; t < 32; ++t){ acc0[t]=0.f; acc1[t]=0.f; }
    for (int i = 0; i < Hv; ++i){
        float hr[36];
        const float4* lp = (const float4*)&lh[i*36];
        #pragma unroll
        for (int q = 0; q < 9; ++q){
            float4 v = lp[q];
            hr[4*q]=v.x; hr[4*q+1]=v.y; hr[4*q+2]=v.z; hr[4*q+3]=v.w;
        }
        const float* wp = Wt + i*Hv;
        float w00 = wp[o0], w01 = wp[Hv*Hv + o0], w02 = wp[2*Hv*Hv + o0];
        float w10 = wp[o1], w11 = wp[Hv*Hv + o1], w12 = wp[2*Hv*Hv + o1];
        #pragma unroll
        for (int t = 0; t < 32; ++t){
            acc0[t]=fmaf(w00,hr[t],acc0[t]);
            acc0[t]=fmaf(w01,hr[t+1],acc0[t]);
            acc0[t]=fmaf(w02,hr[t+2],acc0[t]);
            acc1[t]=fmaf(w10,hr[t],acc1[t]);
            acc1[t]=fmaf(w11,hr[t+1],acc1[t]);
            acc1[t]=fmaf(w12,hr[t+2],acc1[t]);
        }
    }
    float bb0 = btm[o0], bb1 = btm[o1];
    for (int t = 0; t < 32; ++t){
        int idx = ((b*Tv + t)*Nv + n)*Hv;
        float g0 = gelu_exact(acc0[t] + bb0);
        float g1 = gelu_exact(acc1[t] + bb1);
        out[idx + o0] = g0 + out[idx + o0];   // residual already in d_out
        out[idx + o1] = g1 + out[idx + o1];
    }
}

// ---- LayerNorm over H=128, one wave per row ----
__global__ __launch_bounds__(64) void k_ln(float* __restrict__ out,
        const float* __restrict__ lw, const float* __restrict__ lb){
    int lane = threadIdx.x;
    int base = blockIdx.x * Hv;
    float v0 = out[base + lane], v1 = out[base + 64 + lane];
    float s = v0 + v1, ss = v0*v0 + v1*v1;
    #pragma unroll
    for (int m = 32; m >= 1; m >>= 1){
        s  += __shfl_xor(s,  m, 64);
        ss += __shfl_xor(ss, m, 64);
    }
    float mean = s*(1.f/128.f);
    float var  = fmaxf(ss*(1.f/128.f) - mean*mean, 0.f);
    float rstd = rsqrtf(var + 1e-5f);
    out[base + lane]      = (v0 - mean)*rstd*lw[lane]      + lb[lane];
    out[base + 64 + lane] = (v1 - mean)*rstd*lw[64 + lane] + lb[64 + lane];
}

extern "C" void kernel_launch(void* const* d_in, const int* in_sizes, int n_in,
                              void* d_out, int out_size, void* d_ws, size_t ws_size,
                              hipStream_t stream){
    const float* x   = (const float*)d_in[0];
    const int*   ei  = (const int*)d_in[1];
    const float* ew  = (const float*)d_in[2];
    const float* Wg  = (const float*)d_in[3];
    const float* bg  = (const float*)d_in[4];
    const float* Wtm = (const float*)d_in[5];
    const float* btm = (const float*)d_in[6];
    const float* lw  = (const float*)d_in[7];
    const float* lb  = (const float*)d_in[8];
    const float* Wr  = (const float*)d_in[9];
    const float* br  = (const float*)d_in[10];
    float* out = (float*)d_out;

    char* ws = (char*)d_ws;
    float* deg    = (float*)(ws + 0);          // 2048 B
    int*   counts = (int*)  (ws + 2048);       // 2048 B
    float* dinv   = (float*)(ws + 4096);       // 2048 B
    int*   offs   = (int*)  (ws + 6144);       // 2048 B
    int*   cursor = (int*)  (ws + 8192);       // 2048 B
    int*   csrc   = (int*)  (ws + 10240);      // 32768 B
    float* cwn    = (float*)(ws + 43008);      // 32768 B
    float* Wt     = (float*)(ws + 75776);      // 196608 B
    float* xf     = (float*)(ws + 272384);     // 65.5 MB
    float* hgp    = (float*)(ws + 272384 + (size_t)ROWS*Hv*4);  // 69.6 MB

    hipMemsetAsync(ws, 0, 4096, stream);  // deg + counts

    k_graph  <<<(Ev+Nv+255)/256, 256, 0, stream>>>(ei, ew, deg, counts);
    k_scan   <<<1, 512, 0, stream>>>(deg, counts, dinv, offs, cursor);
    k_fill   <<<(Ev+255)/256, 256, 0, stream>>>(ei, ew, dinv, cursor, csrc, cwn);
    k_wt     <<<(Hv*Hv*Kv+255)/256, 256, 0, stream>>>(Wtm, Wt);
    k_gemm_in<<<ROWS/16, 64, 0, stream>>>(x, Wg, Wr, br, xf, out);
    k_pad    <<<(Bv*Nv*2*Hv+255)/256, 256, 0, stream>>>(hgp);
    k_gather <<<ROWS, 128, 0, stream>>>(xf, dinv, offs, csrc, cwn, bg, hgp);
    k_conv   <<<Bv*Nv, 64, 0, stream>>>(hgp, Wt, btm, out);
    k_ln     <<<ROWS, 64, 0, stream>>>(out, lw, lb);
}

// Round 2
// 413.512 us; speedup vs baseline: 1.4907x; 1.4907x over previous
//
#include <hip/hip_runtime.h>
#include <hip/hip_bf16.h>
#include <math.h>

#define Bv 8
#define Tv 32
#define Nv 500
#define Fin 64
#define Hv 128
#define Ev 8000
#define Kv 3
#define BT (Bv*Tv)      /* 256 */
#define ROWS (BT*Nv)    /* 128000 */
#define TP (Tv+2)       /* 34 padded time steps */
#define KK (Kv*Hv)      /* 384: flattened conv K dim */
#define LDSROW 136      /* padded LDS row stride in bf16 elems (272B -> bank stride 4, 2-way) */

typedef __attribute__((ext_vector_type(8))) short s8v;   // 8 bf16 = 4 VGPRs
typedef __attribute__((ext_vector_type(4))) float f4v;   // MFMA acc

__device__ __forceinline__ float gelu_exact(float v){
    return 0.5f*v*(1.0f + erff(v*0.70710678118654752440f));
}

// ---- graph prep: weighted degree (incl. self loop) + per-dst edge counts ----
__global__ void k_graph(const int* ei, const float* ew, float* deg, int* counts){
    int idx = blockIdx.x*256 + threadIdx.x;
    if (idx < Ev){
        int d = ei[Ev + idx];
        atomicAdd(&deg[d], ew[idx]);
        atomicAdd(&counts[d], 1);
    } else if (idx < Ev + Nv){
        atomicAdd(&deg[idx - Ev], 1.0f);   // self loop weight 1
    }
}

// ---- dinv + exclusive scan of counts -> CSR offsets (N=500 fits one block) ----
__global__ void k_scan(const float* deg, const int* counts, float* dinv, int* offs, int* cursor){
    __shared__ int sa[512], sb[512];
    int tid = threadIdx.x;
    int c = (tid < Nv) ? counts[tid] : 0;
    if (tid < Nv){
        float d = deg[tid];
        dinv[tid] = (d > 0.f) ? rsqrtf(d) : 0.f;
    }
    sa[tid] = c; __syncthreads();
    int* s = sa; int* t = sb;
    for (int off = 1; off < 512; off <<= 1){
        int v = s[tid];
        if (tid >= off) v += s[tid - off];
        t[tid] = v; __syncthreads();
        int* tmp = s; s = t; t = tmp;
    }
    int excl = s[tid] - c;
    if (tid < Nv){ offs[tid] = excl; cursor[tid] = excl; }
    if (tid == 0) offs[Nv] = Ev;
}

// ---- fill CSR (src id + normalized weight dinv[src]*ew*dinv[dst]) ----
__global__ void k_fill(const int* ei, const float* ew, const float* dinv,
                       int* cursor, int* csrc, float* cw){
    int e = blockIdx.x*256 + threadIdx.x;
    if (e >= Ev) return;
    int s = ei[e], d = ei[Ev + e];
    int pos = atomicAdd(&cursor[d], 1);
    csrc[pos] = s;
    cw[pos] = dinv[s]*ew[e]*dinv[d];
}

// ---- W_temp (O,I,K) fp32 -> W2[o][k*128+i] bf16 (MFMA B-operand friendly) ----
__global__ void k_w2(const float* W, __hip_bfloat16* W2){
    int idx = blockIdx.x*256 + threadIdx.x;
    if (idx >= Hv*Hv*Kv) return;
    int o = idx/(Hv*Kv);
    int rem = idx - o*(Hv*Kv);
    int i = rem/Kv, k = rem - i*Kv;
    W2[o*KK + k*Hv + i] = __float2bfloat16(W[idx]);
}

// ---- fused input GEMMs: xf = x@Wg (to ws), res = x@Wr + br (to d_out) ----
__global__ __launch_bounds__(64) void k_gemm_in(const float* __restrict__ x,
        const float* __restrict__ Wg, const float* __restrict__ Wr,
        const float* __restrict__ br, float* __restrict__ xf, float* __restrict__ outres){
    __shared__ float xs[16*64];
    int lane = threadIdx.x;
    int row0 = blockIdx.x * 16;
    const float* xp = x + row0*Fin;
    for (int j = lane; j < 16*64; j += 64) xs[j] = xp[j];
    __syncthreads();
    int h0 = lane, h1 = lane + 64;
    float a0[16], a1[16], r0[16], r1[16];
    #pragma unroll
    for (int r = 0; r < 16; ++r){ a0[r]=0.f; a1[r]=0.f; r0[r]=0.f; r1[r]=0.f; }
    for (int k4 = 0; k4 < 16; ++k4){
        float wg0[4], wg1[4], wr0[4], wr1[4];
        #pragma unroll
        for (int q = 0; q < 4; ++q){
            int k = 4*k4 + q;
            wg0[q] = Wg[k*Hv + h0]; wg1[q] = Wg[k*Hv + h1];
            wr0[q] = Wr[k*Hv + h0]; wr1[q] = Wr[k*Hv + h1];
        }
        #pragma unroll
        for (int r = 0; r < 16; ++r){
            float4 xq = *(const float4*)&xs[r*64 + 4*k4];
            a0[r]=fmaf(xq.x,wg0[0],a0[r]); a0[r]=fmaf(xq.y,wg0[1],a0[r]);
            a0[r]=fmaf(xq.z,wg0[2],a0[r]); a0[r]=fmaf(xq.w,wg0[3],a0[r]);
            a1[r]=fmaf(xq.x,wg1[0],a1[r]); a1[r]=fmaf(xq.y,wg1[1],a1[r]);
            a1[r]=fmaf(xq.z,wg1[2],a1[r]); a1[r]=fmaf(xq.w,wg1[3],a1[r]);
            r0[r]=fmaf(xq.x,wr0[0],r0[r]); r0[r]=fmaf(xq.y,wr0[1],r0[r]);
            r0[r]=fmaf(xq.z,wr0[2],r0[r]); r0[r]=fmaf(xq.w,wr0[3],r0[r]);
            r1[r]=fmaf(xq.x,wr1[0],r1[r]); r1[r]=fmaf(xq.y,wr1[1],r1[r]);
            r1[r]=fmaf(xq.z,wr1[2],r1[r]); r1[r]=fmaf(xq.w,wr1[3],r1[r]);
        }
    }
    float b0 = br[h0], b1 = br[h1];
    #pragma unroll
    for (int r = 0; r < 16; ++r){
        int rr = (row0 + r)*Hv;
        xf[rr + h0] = a0[r]; xf[rr + h1] = a1[r];
        outres[rr + h0] = r0[r] + b0; outres[rr + h1] = r1[r] + b1;
    }
}

// ---- zero the t=0 / t=TP-1 pad planes of hgp (bf16) ----
__global__ void k_pad(__hip_bfloat16* hgp){
    int idx = blockIdx.x*256 + threadIdx.x;
    if (idx >= Bv*Nv*2*Hv) return;
    int h  = idx & 127;
    int r  = (idx >> 7) & 1;
    int bn = idx >> 8;
    hgp[(bn*TP + r*(TP-1))*Hv + h] = __float2bfloat16(0.f);
}

// ---- GCN aggregate (gather over CSR) + bias + exact GELU -> bf16 hgp (b,n,tpad,h) ----
__global__ __launch_bounds__(128) void k_gather(const float* __restrict__ xf,
        const float* __restrict__ dinv, const int* __restrict__ offs,
        const int* __restrict__ csrc, const float* __restrict__ cw,
        const float* __restrict__ bg, __hip_bfloat16* __restrict__ hgp){
    int bid = blockIdx.x;
    int h = threadIdx.x;
    int bt = bid / Nv;          // consecutive blocks share bt -> xf slice hot in L2
    int n = bid - bt*Nv;
    int b = bt >> 5, t = bt & 31;
    const float* xb = xf + bt*Nv*Hv;
    float dv = dinv[n];
    float acc = dv*dv*xb[n*Hv + h];            // self loop
    int e0 = offs[n], e1 = offs[n+1];
    for (int e = e0; e < e1; ++e)
        acc = fmaf(cw[e], xb[csrc[e]*Hv + h], acc);
    float v = acc + bg[h];
    hgp[((b*Nv + n)*TP + (t + 1))*Hv + h] = __float2bfloat16(gelu_exact(v));
}

// ---- MFMA temporal conv (K=3 as GEMM M=32,N=128,K=384) + bias + GELU
//      + residual (from d_out) + fused LayerNorm -> d_out ----
// block = 256 threads (4 waves), handles 4 graph nodes; grid = B*N/4 = 1000.
// wave w owns output channels [w*32, w*32+32); B fragments live in regs across nodes.
__global__ __launch_bounds__(256, 2) void k_conv(const __hip_bfloat16* __restrict__ hgp,
        const __hip_bfloat16* __restrict__ W2, const float* __restrict__ btm,
        const float* __restrict__ lw, const float* __restrict__ lb,
        float* __restrict__ out){
    __shared__ short hs[4*TP*LDSROW];      // 4 nodes, padded rows: 36992 B
    __shared__ float red[Tv][4][2];        // per-row (sum, sumsq) partial per wave
    int tid  = threadIdx.x;
    int w    = tid >> 6;
    int lane = tid & 63;
    int quad = lane >> 4;
    int laneo = lane & 15;
    int bid = blockIdx.x;
    int b  = bid / 125;
    int n0 = (bid - b*125) * 4;

    // ---- stage 4 node windows (34x128 bf16 each) into LDS, row stride 136 ----
    const short* hp = (const short*)hgp + (size_t)(b*Nv + n0)*TP*Hv;
    for (int j = tid; j < 4*TP*16; j += 256){        // 16B chunks: 2176 total
        int node = j / (TP*16);
        int rem  = j - node*(TP*16);
        int tp = rem >> 4, c8 = rem & 15;
        s8v v = ((const s8v*)hp)[j];
        *(s8v*)&hs[node*(TP*LDSROW) + tp*LDSROW + c8*8] = v;
    }

    // ---- load B fragments for this wave's 2 n-tiles (kept across all 4 nodes) ----
    s8v breg[2][12];
    #pragma unroll
    for (int nt = 0; nt < 2; ++nt){
        int o = w*32 + nt*16 + laneo;
        const short* wp = (const short*)W2 + o*KK + quad*8;
        #pragma unroll
        for (int s = 0; s < 12; ++s)
            breg[nt][s] = *(const s8v*)(wp + s*32);
    }
    float bb[2], lwv[2], lbv[2];
    #pragma unroll
    for (int nt = 0; nt < 2; ++nt){
        int o = w*32 + nt*16 + laneo;
        bb[nt] = btm[o]; lwv[nt] = lw[o]; lbv[nt] = lb[o];
    }
    __syncthreads();

    for (int g = 0; g < 4; ++g){
        int n = n0 + g;
        // ---- MFMA main loop: 2 m-tiles x 12 K-steps x 2 n-tiles ----
        f4v acc[2][2];
        #pragma unroll
        for (int m = 0; m < 2; ++m)
            #pragma unroll
            for (int nt = 0; nt < 2; ++nt)
                acc[m][nt] = (f4v){0.f,0.f,0.f,0.f};
        #pragma unroll
        for (int m = 0; m < 2; ++m){
            #pragma unroll
            for (int s = 0; s < 12; ++s){
                int k  = s >> 2;
                int i0 = (s & 3) * 32;
                int tp = m*16 + laneo + k;         // t + conv_k (pad already applied)
                s8v a = *(const s8v*)&hs[g*(TP*LDSROW) + tp*LDSROW + i0 + quad*8];
                acc[m][0] = __builtin_amdgcn_mfma_f32_16x16x32_bf16(a, breg[0][s], acc[m][0], 0,0,0);
                acc[m][1] = __builtin_amdgcn_mfma_f32_16x16x32_bf16(a, breg[1][s], acc[m][1], 0,0,0);
            }
        }
        // ---- epilogue: bias+GELU+residual, per-row LN stats ----
        size_t obase = ((size_t)b*Tv*Nv + n)*Hv;   // + t*Nv*Hv + o
        float yv[2][2][4];
        float srow[2][4], ssrow[2][4];
        #pragma unroll
        for (int m = 0; m < 2; ++m)
            #pragma unroll
            for (int r = 0; r < 4; ++r){ srow[m][r] = 0.f; ssrow[m][r] = 0.f; }
        #pragma unroll
        for (int m = 0; m < 2; ++m){
            #pragma unroll
            for (int nt = 0; nt < 2; ++nt){
                int o = w*32 + nt*16 + laneo;
                #pragma unroll
                for (int r = 0; r < 4; ++r){
                    int t = m*16 + quad*4 + r;
                    float gv = gelu_exact(acc[m][nt][r] + bb[nt]);
                    float y = gv + out[obase + (size_t)t*Nv*Hv + o];
                    yv[m][nt][r] = y;
                    srow[m][r] += y; ssrow[m][r] += y*y;
                }
            }
        }
        // reduce over the 16 lanes of each quad (covers this wave's 32 channels)
        #pragma unroll
        for (int m = 0; m < 2; ++m)
            #pragma unroll
            for (int r = 0; r < 4; ++r){
                #pragma unroll
                for (int msk = 8; msk >= 1; msk >>= 1){
                    srow[m][r]  += __shfl_xor(srow[m][r],  msk, 64);
                    ssrow[m][r] += __shfl_xor(ssrow[m][r], msk, 64);
                }
            }
        if (laneo == 0){
            #pragma unroll
            for (int m = 0; m < 2; ++m)
                #pragma unroll
                for (int r = 0; r < 4; ++r){
                    int t = m*16 + quad*4 + r;
                    red[t][w][0] = srow[m][r];
                    red[t][w][1] = ssrow[m][r];
                }
        }
        __syncthreads();
        // ---- finalize LN and write ----
        #pragma unroll
        for (int m = 0; m < 2; ++m){
            #pragma unroll
            for (int r = 0; r < 4; ++r){
                int t = m*16 + quad*4 + r;
                float s  = red[t][0][0] + red[t][1][0] + red[t][2][0] + red[t][3][0];
                float ss = red[t][0][1] + red[t][1][1] + red[t][2][1] + red[t][3][1];
                float mu = s * (1.f/128.f);
                float var = fmaxf(ss * (1.f/128.f) - mu*mu, 0.f);
                float rstd = rsqrtf(var + 1e-5f);
                #pragma unroll
                for (int nt = 0; nt < 2; ++nt){
                    int o = w*32 + nt*16 + laneo;
                    out[obase + (size_t)t*Nv*Hv + o] =
                        (yv[m][nt][r] - mu)*rstd*lwv[nt] + lbv[nt];
                }
            }
        }
        __syncthreads();   // protect red[] reuse by next node
    }
}

extern "C" void kernel_launch(void* const* d_in, const int* in_sizes, int n_in,
                              void* d_out, int out_size, void* d_ws, size_t ws_size,
                              hipStream_t stream){
    const float* x   = (const float*)d_in[0];
    const int*   ei  = (const int*)d_in[1];
    const float* ew  = (const float*)d_in[2];
    const float* Wg  = (const float*)d_in[3];
    const float* bg  = (const float*)d_in[4];
    const float* Wtm = (const float*)d_in[5];
    const float* btm = (const float*)d_in[6];
    const float* lw  = (const float*)d_in[7];
    const float* lb  = (const float*)d_in[8];
    const float* Wr  = (const float*)d_in[9];
    const float* br  = (const float*)d_in[10];
    float* out = (float*)d_out;

    char* ws = (char*)d_ws;
    float* deg    = (float*)(ws + 0);          // 2048 B
    int*   counts = (int*)  (ws + 2048);       // 2048 B
    float* dinv   = (float*)(ws + 4096);       // 2048 B
    int*   offs   = (int*)  (ws + 6144);       // 2048 B
    int*   cursor = (int*)  (ws + 8192);       // 2048 B
    int*   csrc   = (int*)  (ws + 10240);      // 32768 B
    float* cwn    = (float*)(ws + 43008);      // 32768 B
    __hip_bfloat16* W2 = (__hip_bfloat16*)(ws + 75776);   // 98304 B
    float* xf     = (float*)(ws + 272384);     // 65.5 MB fp32
    __hip_bfloat16* hgp = (__hip_bfloat16*)(ws + 272384 + (size_t)ROWS*Hv*4); // 34.8 MB bf16

    hipMemsetAsync(ws, 0, 4096, stream);  // deg + counts

    k_graph  <<<(Ev+Nv+255)/256, 256, 0, stream>>>(ei, ew, deg, counts);
    k_scan   <<<1, 512, 0, stream>>>(deg, counts, dinv, offs, cursor);
    k_fill   <<<(Ev+255)/256, 256, 0, stream>>>(ei, ew, dinv, cursor, csrc, cwn);
    k_w2     <<<(Hv*Hv*Kv+255)/256, 256, 0, stream>>>(Wtm, W2);
    k_gemm_in<<<ROWS/16, 64, 0, stream>>>(x, Wg, Wr, br, xf, out);
    k_pad    <<<(Bv*Nv*2*Hv+255)/256, 256, 0, stream>>>(hgp);
    k_gather <<<ROWS, 128, 0, stream>>>(xf, dinv, offs, csrc, cwn, bg, hgp);
    k_conv   <<<(Bv*Nv)/4, 256, 0, stream>>>(hgp, W2, btm, lw, lb, out);
}

// Round 3
// 246.887 us; speedup vs baseline: 2.4967x; 1.6749x over previous
//
#include <hip/hip_runtime.h>
#include <hip/hip_bf16.h>
#include <math.h>

#define Bv 8
#define Tv 32
#define Nv 500
#define Fin 64
#define Hv 128
#define Ev 8000
#define Kv 3
#define BT (Bv*Tv)      /* 256 */
#define ROWS (BT*Nv)    /* 128000 */
#define TP (Tv+2)       /* 34 LDS time rows (1 pad each side) */
#define KK (Kv*Hv)      /* 384: flattened conv K dim */
#define LDSROW 136      /* padded LDS row stride in bf16 (272B -> bank stride 4, 2-way free) */

typedef __attribute__((ext_vector_type(8))) short s8v;   // 8 bf16 = 4 VGPRs
typedef __attribute__((ext_vector_type(4))) float f4v;   // MFMA acc

__device__ __forceinline__ float gelu_exact(float v){
    return 0.5f*v*(1.0f + erff(v*0.70710678118654752440f));
}
__device__ __forceinline__ short f2bs(float f){
    union { __hip_bfloat16 h; short s; } u;
    u.h = __float2bfloat16(f);
    return u.s;
}
__device__ __forceinline__ float b2f(short s){
    union { unsigned int i; float f; } u;
    u.i = ((unsigned int)(unsigned short)s) << 16;
    return u.f;
}

// ---- graph prep: weighted degree (incl. self loop) + per-dst edge counts ----
__global__ void k_graph(const int* ei, const float* ew, float* deg, int* counts){
    int idx = blockIdx.x*256 + threadIdx.x;
    if (idx < Ev){
        int d = ei[Ev + idx];
        atomicAdd(&deg[d], ew[idx]);
        atomicAdd(&counts[d], 1);
    } else if (idx < Ev + Nv){
        atomicAdd(&deg[idx - Ev], 1.0f);   // self loop weight 1
    }
}

// ---- dinv + exclusive scan of counts -> CSR offsets (N=500 fits one block) ----
__global__ void k_scan(const float* deg, const int* counts, float* dinv, int* offs, int* cursor){
    __shared__ int sa[512], sb[512];
    int tid = threadIdx.x;
    int c = (tid < Nv) ? counts[tid] : 0;
    if (tid < Nv){
        float d = deg[tid];
        dinv[tid] = (d > 0.f) ? rsqrtf(d) : 0.f;
    }
    sa[tid] = c; __syncthreads();
    int* s = sa; int* t = sb;
    for (int off = 1; off < 512; off <<= 1){
        int v = s[tid];
        if (tid >= off) v += s[tid - off];
        t[tid] = v; __syncthreads();
        int* tmp = s; s = t; t = tmp;
    }
    int excl = s[tid] - c;
    if (tid < Nv){ offs[tid] = excl; cursor[tid] = excl; }
    if (tid == 0) offs[Nv] = Ev;
}

// ---- fill CSR (src id + normalized weight dinv[src]*ew*dinv[dst]) ----
__global__ void k_fill(const int* ei, const float* ew, const float* dinv,
                       int* cursor, int* csrc, float* cw){
    int e = blockIdx.x*256 + threadIdx.x;
    if (e >= Ev) return;
    int s = ei[e], d = ei[Ev + e];
    int pos = atomicAdd(&cursor[d], 1);
    csrc[pos] = s;
    cw[pos] = dinv[s]*ew[e]*dinv[d];
}

// ---- weight prep (all bf16): W2[o][k*128+i], Wgt[o][k], Wrt[o][k] ----
__global__ void k_wprep(const float* W, const float* Wg, const float* Wr,
                        short* W2, short* Wgt, short* Wrt){
    int idx = blockIdx.x*256 + threadIdx.x;
    if (idx < Hv*Hv*Kv){
        int o = idx/(Hv*Kv);
        int rem = idx - o*(Hv*Kv);
        int i = rem/Kv, k = rem - i*Kv;
        W2[o*KK + k*Hv + i] = f2bs(W[idx]);
    } else if (idx < Hv*Hv*Kv + Hv*64){
        int j = idx - Hv*Hv*Kv;
        int o = j >> 6, k = j & 63;
        Wgt[j] = f2bs(Wg[k*Hv + o]);
    } else if (idx < Hv*Hv*Kv + 2*Hv*64){
        int j = idx - Hv*Hv*Kv - Hv*64;
        int o = j >> 6, k = j & 63;
        Wrt[j] = f2bs(Wr[k*Hv + o]);
    }
}

// ---- x (bt,n,c) fp32 -> X2b (n, bt*64+c) bf16  AND  xb (btn, c) bf16 ----
__global__ __launch_bounds__(256) void k_xpose(const float* __restrict__ x,
        short* __restrict__ X2b, short* __restrict__ xb){
    int gid = blockIdx.x*256 + threadIdx.x;     // one float4; total ROWS*16
    int row = gid >> 4, c4 = gid & 15;
    int bt = row / Nv;
    int n  = row - bt*Nv;
    float4 v = ((const float4*)x)[gid];
    short4 s;
    s.x = f2bs(v.x); s.y = f2bs(v.y); s.z = f2bs(v.z); s.w = f2bs(v.w);
    *(short4*)(xb + (size_t)row*64 + c4*4) = s;
    *(short4*)(X2b + (size_t)n*(BT*64) + bt*64 + c4*4) = s;
}

// ---- dense-row SpMM: AGG2[n, btc] = dv^2*X2b[n] + sum_e w_e * X2b[src_e] ----
// grid = 8 column-tiles x 500 nodes, column-tile-major for L2 slab reuse.
__global__ __launch_bounds__(256) void k_spmm(const short* __restrict__ X2b,
        const float* __restrict__ dinv, const int* __restrict__ offs,
        const int* __restrict__ csrc, const float* __restrict__ cw,
        short* __restrict__ AGG2){
    int bid = blockIdx.x;
    int ct = bid / Nv;
    int n  = bid - ct*Nv;
    int col = ct*2048 + threadIdx.x*8;
    float dv = dinv[n];
    float sw = dv*dv;
    float acc[8];
    s8v v = *(const s8v*)(X2b + (size_t)n*(BT*64) + col);
    #pragma unroll
    for (int q = 0; q < 8; ++q) acc[q] = sw * b2f(v[q]);
    int e0 = offs[n], e1 = offs[n+1];
    for (int e = e0; e < e1; ++e){
        int s = csrc[e]; float w = cw[e];
        s8v u = *(const s8v*)(X2b + (size_t)s*(BT*64) + col);
        #pragma unroll
        for (int q = 0; q < 8; ++q) acc[q] = fmaf(w, b2f(u[q]), acc[q]);
    }
    s8v r;
    #pragma unroll
    for (int q = 0; q < 8; ++q) r[q] = f2bs(acc[q]);
    *(s8v*)(AGG2 + (size_t)n*(BT*64) + col) = r;
}

// ---- MFMA GEMM: hgp[(n,bt), o] = gelu(AGG2 @ Wg + bg), bf16, 1 wave/block ----
__global__ __launch_bounds__(64) void k_gemm_gcn(const short* __restrict__ AGG2,
        const short* __restrict__ Wgt, const float* __restrict__ bg,
        short* __restrict__ hgp){
    __shared__ short ls[16*Hv];
    int lane = threadIdx.x;
    int laneo = lane & 15, quad = lane >> 4;
    int r0 = blockIdx.x * 16;
    const short* ap = AGG2 + (size_t)(r0 + laneo)*64 + quad*8;
    s8v a0 = *(const s8v*)ap;
    s8v a1 = *(const s8v*)(ap + 32);
    const short* wp = Wgt + laneo*64 + quad*8;
    f4v acc[8];
    #pragma unroll
    for (int nt = 0; nt < 8; ++nt){
        s8v b0 = *(const s8v*)(wp + nt*1024);
        s8v b1 = *(const s8v*)(wp + nt*1024 + 32);
        f4v z = {0.f,0.f,0.f,0.f};
        acc[nt] = __builtin_amdgcn_mfma_f32_16x16x32_bf16(a0, b0, z, 0,0,0);
        acc[nt] = __builtin_amdgcn_mfma_f32_16x16x32_bf16(a1, b1, acc[nt], 0,0,0);
    }
    #pragma unroll
    for (int nt = 0; nt < 8; ++nt){
        int o = nt*16 + laneo;
        float bb = bg[o];
        #pragma unroll
        for (int r = 0; r < 4; ++r){
            int row = quad*4 + r;                 // C layout: row=quad*4+r, col=laneo
            ls[row*Hv + o] = f2bs(gelu_exact(acc[nt][r] + bb));
        }
    }
    __syncthreads();
    short* dst = hgp + (size_t)r0*Hv;
    #pragma unroll
    for (int it = 0; it < 4; ++it){
        int j = it*64 + lane;
        *(s8v*)(dst + j*8) = *(const s8v*)&ls[j*8];
    }
}

// ---- MFMA GEMM: out[btn, o] = xb @ Wr + br, fp32 ----
__global__ __launch_bounds__(64) void k_gemm_res(const short* __restrict__ xb,
        const short* __restrict__ Wrt, const float* __restrict__ br,
        float* __restrict__ out){
    __shared__ float ls[16*Hv];
    int lane = threadIdx.x;
    int laneo = lane & 15, quad = lane >> 4;
    int r0 = blockIdx.x * 16;
    const short* ap = xb + (size_t)(r0 + laneo)*64 + quad*8;
    s8v a0 = *(const s8v*)ap;
    s8v a1 = *(const s8v*)(ap + 32);
    const short* wp = Wrt + laneo*64 + quad*8;
    f4v acc[8];
    #pragma unroll
    for (int nt = 0; nt < 8; ++nt){
        s8v b0 = *(const s8v*)(wp + nt*1024);
        s8v b1 = *(const s8v*)(wp + nt*1024 + 32);
        f4v z = {0.f,0.f,0.f,0.f};
        acc[nt] = __builtin_amdgcn_mfma_f32_16x16x32_bf16(a0, b0, z, 0,0,0);
        acc[nt] = __builtin_amdgcn_mfma_f32_16x16x32_bf16(a1, b1, acc[nt], 0,0,0);
    }
    #pragma unroll
    for (int nt = 0; nt < 8; ++nt){
        int o = nt*16 + laneo;
        float bb = br[o];
        #pragma unroll
        for (int r = 0; r < 4; ++r){
            int row = quad*4 + r;
            ls[row*Hv + o] = acc[nt][r] + bb;
        }
    }
    __syncthreads();
    float* dst = out + (size_t)r0*Hv;
    #pragma unroll
    for (int it = 0; it < 8; ++it){
        int j = it*64 + lane;
        *(float4*)(dst + j*4) = *(const float4*)&ls[j*4];
    }
}

// ---- MFMA temporal conv (M=32,N=128,K=384) + bias + GELU + residual + LN ----
// hgp rows are (n*256 + bt); window for (b,n) = 32 contiguous rows. Pads
// zero-filled in LDS. block = 4 waves, 4 nodes; wave w owns channels [w*32,+32).
__global__ __launch_bounds__(256, 2) void k_conv(const short* __restrict__ hgp,
        const short* __restrict__ W2, const float* __restrict__ btm,
        const float* __restrict__ lw, const float* __restrict__ lb,
        float* __restrict__ out){
    __shared__ short hs[4*TP*LDSROW];      // 36992 B
    __shared__ float red[Tv][4][2];
    int tid  = threadIdx.x;
    int w    = tid >> 6;
    int lane = tid & 63;
    int quad = lane >> 4;
    int laneo = lane & 15;
    int bid = blockIdx.x;
    int b  = bid / 125;
    int n0 = (bid - b*125) * 4;

    // ---- stage 4 windows (32x128 bf16, contiguous) + zero pad rows ----
    const short* hbase = hgp + ((size_t)n0*BT + b*Tv)*Hv;
    for (int j = tid; j < 4*Tv*16; j += 256){
        int node = j >> 9;
        int rem  = j & 511;                  // t*16 + c8
        s8v v = *(const s8v*)(hbase + (size_t)node*BT*Hv + rem*8);
        int tp = (rem >> 4) + 1, c8 = rem & 15;
        *(s8v*)&hs[node*(TP*LDSROW) + tp*LDSROW + c8*8] = v;
    }
    if (tid < 128){
        int node = tid >> 5, rem = tid & 31;
        int tp = (rem >> 4) * (TP-1), c8 = rem & 15;
        s8v z = {0,0,0,0,0,0,0,0};
        *(s8v*)&hs[node*(TP*LDSROW) + tp*LDSROW + c8*8] = z;
    }

    // ---- B fragments for this wave's 2 n-tiles (kept across 4 nodes) ----
    s8v breg[2][12];
    #pragma unroll
    for (int nt = 0; nt < 2; ++nt){
        int o = w*32 + nt*16 + laneo;
        const short* wp = W2 + o*KK + quad*8;
        #pragma unroll
        for (int s = 0; s < 12; ++s)
            breg[nt][s] = *(const s8v*)(wp + s*32);
    }
    float bb[2], lwv[2], lbv[2];
    #pragma unroll
    for (int nt = 0; nt < 2; ++nt){
        int o = w*32 + nt*16 + laneo;
        bb[nt] = btm[o]; lwv[nt] = lw[o]; lbv[nt] = lb[o];
    }
    __syncthreads();

    for (int g = 0; g < 4; ++g){
        int n = n0 + g;
        f4v acc[2][2];
        #pragma unroll
        for (int m = 0; m < 2; ++m)
            #pragma unroll
            for (int nt = 0; nt < 2; ++nt)
                acc[m][nt] = (f4v){0.f,0.f,0.f,0.f};
        #pragma unroll
        for (int m = 0; m < 2; ++m){
            #pragma unroll
            for (int s = 0; s < 12; ++s){
                int k  = s >> 2;
                int i0 = (s & 3) * 32;
                int tp = m*16 + laneo + k;
                s8v a = *(const s8v*)&hs[g*(TP*LDSROW) + tp*LDSROW + i0 + quad*8];
                acc[m][0] = __builtin_amdgcn_mfma_f32_16x16x32_bf16(a, breg[0][s], acc[m][0], 0,0,0);
                acc[m][1] = __builtin_amdgcn_mfma_f32_16x16x32_bf16(a, breg[1][s], acc[m][1], 0,0,0);
            }
        }
        size_t obase = ((size_t)b*Tv*Nv + n)*Hv;
        float yv[2][2][4];
        float srow[2][4], ssrow[2][4];
        #pragma unroll
        for (int m = 0; m < 2; ++m)
            #pragma unroll
            for (int r = 0; r < 4; ++r){ srow[m][r] = 0.f; ssrow[m][r] = 0.f; }
        #pragma unroll
        for (int m = 0; m < 2; ++m){
            #pragma unroll
            for (int nt = 0; nt < 2; ++nt){
                int o = w*32 + nt*16 + laneo;
                #pragma unroll
                for (int r = 0; r < 4; ++r){
                    int t = m*16 + quad*4 + r;
                    float gv = gelu_exact(acc[m][nt][r] + bb[nt]);
                    float y = gv + out[obase + (size_t)t*Nv*Hv + o];
                    yv[m][nt][r] = y;
                    srow[m][r] += y; ssrow[m][r] += y*y;
                }
            }
        }
        #pragma unroll
        for (int m = 0; m < 2; ++m)
            #pragma unroll
            for (int r = 0; r < 4; ++r){
                #pragma unroll
                for (int msk = 8; msk >= 1; msk >>= 1){
                    srow[m][r]  += __shfl_xor(srow[m][r],  msk, 64);
                    ssrow[m][r] += __shfl_xor(ssrow[m][r], msk, 64);
                }
            }
        if (laneo == 0){
            #pragma unroll
            for (int m = 0; m < 2; ++m)
                #pragma unroll
                for (int r = 0; r < 4; ++r){
                    int t = m*16 + quad*4 + r;
                    red[t][w][0] = srow[m][r];
                    red[t][w][1] = ssrow[m][r];
                }
        }
        __syncthreads();
        #pragma unroll
        for (int m = 0; m < 2; ++m){
            #pragma unroll
            for (int r = 0; r < 4; ++r){
                int t = m*16 + quad*4 + r;
                float s  = red[t][0][0] + red[t][1][0] + red[t][2][0] + red[t][3][0];
                float ss = red[t][0][1] + red[t][1][1] + red[t][2][1] + red[t][3][1];
                float mu = s * (1.f/128.f);
                float var = fmaxf(ss * (1.f/128.f) - mu*mu, 0.f);
                float rstd = rsqrtf(var + 1e-5f);
                #pragma unroll
                for (int nt = 0; nt < 2; ++nt){
                    int o = w*32 + nt*16 + laneo;
                    out[obase + (size_t)t*Nv*Hv + o] =
                        (yv[m][nt][r] - mu)*rstd*lwv[nt] + lbv[nt];
                }
            }
        }
        __syncthreads();
    }
}

extern "C" void kernel_launch(void* const* d_in, const int* in_sizes, int n_in,
                              void* d_out, int out_size, void* d_ws, size_t ws_size,
                              hipStream_t stream){
    const float* x   = (const float*)d_in[0];
    const int*   ei  = (const int*)d_in[1];
    const float* ew  = (const float*)d_in[2];
    const float* Wg  = (const float*)d_in[3];
    const float* bg  = (const float*)d_in[4];
    const float* Wtm = (const float*)d_in[5];
    const float* btm = (const float*)d_in[6];
    const float* lw  = (const float*)d_in[7];
    const float* lb  = (const float*)d_in[8];
    const float* Wr  = (const float*)d_in[9];
    const float* br  = (const float*)d_in[10];
    float* out = (float*)d_out;

    char* ws = (char*)d_ws;
    float* deg    = (float*)(ws + 0);
    int*   counts = (int*)  (ws + 2048);
    float* dinv   = (float*)(ws + 4096);
    int*   offs   = (int*)  (ws + 6144);
    int*   cursor = (int*)  (ws + 8192);
    int*   csrc   = (int*)  (ws + 10240);
    float* cwn    = (float*)(ws + 43008);
    short* W2     = (short*)(ws + 75776);       // 98304 B
    short* Wgt    = (short*)(ws + 174080);      // 16384 B
    short* Wrt    = (short*)(ws + 190464);      // 16384 B
    short* X2b    = (short*)(ws + 206848);      // 16.384 MB
    short* xb     = (short*)(ws + 16590848);    // 16.384 MB
    short* AGG2   = (short*)(ws + 32974848);    // 16.384 MB
    short* hgp    = (short*)(ws + 49358848);    // 32.768 MB

    hipMemsetAsync(ws, 0, 4096, stream);  // deg + counts

    k_graph   <<<(Ev+Nv+255)/256, 256, 0, stream>>>(ei, ew, deg, counts);
    k_scan    <<<1, 512, 0, stream>>>(deg, counts, dinv, offs, cursor);
    k_fill    <<<(Ev+255)/256, 256, 0, stream>>>(ei, ew, dinv, cursor, csrc, cwn);
    k_wprep   <<<256, 256, 0, stream>>>(Wtm, Wg, Wr, W2, Wgt, Wrt);
    k_xpose   <<<ROWS/16, 256, 0, stream>>>(x, X2b, xb);
    k_spmm    <<<8*Nv, 256, 0, stream>>>(X2b, dinv, offs, csrc, cwn, AGG2);
    k_gemm_gcn<<<ROWS/16, 64, 0, stream>>>(AGG2, Wgt, bg, hgp);
    k_gemm_res<<<ROWS/16, 64, 0, stream>>>(xb, Wrt, br, out);
    k_conv    <<<(Bv*Nv)/4, 256, 0, stream>>>(hgp, W2, btm, lw, lb, out);
}

// Round 4
// 218.741 us; speedup vs baseline: 2.8180x; 1.1287x over previous
//
#include <hip/hip_runtime.h>
#include <hip/hip_bf16.h>
#include <math.h>

#define Bv 8
#define Tv 32
#define Nv 500
#define Fin 64
#define Hv 128
#define Ev 8000
#define Kv 3
#define BT (Bv*Tv)      /* 256 */
#define ROWS (BT*Nv)    /* 128000 */
#define TP (Tv+2)       /* 34 LDS time rows (1 pad each side) */
#define KK (Kv*Hv)      /* 384: flattened conv K dim */
#define LDSROW 144      /* 288B row stride: bank shift 8 -> 4-way on b128 A-reads */

typedef __attribute__((ext_vector_type(8))) short s8v;   // 8 bf16 = 4 VGPRs
typedef __attribute__((ext_vector_type(4))) float f4v;   // MFMA acc

__device__ __forceinline__ float gelu_exact(float v){
    return 0.5f*v*(1.0f + erff(v*0.70710678118654752440f));
}
__device__ __forceinline__ short f2bs(float f){
    union { __hip_bfloat16 h; short s; } u;
    u.h = __float2bfloat16(f);
    return u.s;
}
__device__ __forceinline__ float b2f(short s){
    union { unsigned int i; float f; } u;
    u.i = ((unsigned int)(unsigned short)s) << 16;
    return u.f;
}

// ---- fused graph prep: degree+counts (LDS atomics), scan, CSR fill. 1 block. ----
__global__ __launch_bounds__(1024) void k_prep(const int* __restrict__ ei,
        const float* __restrict__ ew, float* __restrict__ dinv,
        int* __restrict__ offs, int* __restrict__ csrc, float* __restrict__ cw){
    __shared__ float sdeg[Nv];
    __shared__ int   scnt[Nv];
    __shared__ float sdv[Nv];
    __shared__ int   scur[Nv];
    __shared__ int   sa[512], sb[512];
    int tid = threadIdx.x;
    if (tid < Nv){ sdeg[tid] = 1.0f; scnt[tid] = 0; }   // self-loop weight pre-added
    __syncthreads();
    for (int e = tid; e < Ev; e += 1024){
        int d = ei[Ev + e];
        atomicAdd(&sdeg[d], ew[e]);
        atomicAdd(&scnt[d], 1);
    }
    __syncthreads();
    int c = 0;
    if (tid < Nv){
        float d = sdeg[tid];
        float v = (d > 0.f) ? rsqrtf(d) : 0.f;
        sdv[tid] = v; dinv[tid] = v;
    }
    if (tid < 512){ c = (tid < Nv) ? scnt[tid] : 0; sa[tid] = c; }
    __syncthreads();
    int* s = sa; int* t = sb;
    for (int off = 1; off < 512; off <<= 1){
        int v = 0;
        if (tid < 512){ v = s[tid]; if (tid >= off) v += s[tid - off]; }
        if (tid < 512) t[tid] = v;
        __syncthreads();
        int* tmp = s; s = t; t = tmp;
    }
    if (tid < Nv){ int excl = s[tid] - c; offs[tid] = excl; scur[tid] = excl; }
    if (tid == 0) offs[Nv] = Ev;
    __syncthreads();
    for (int e = tid; e < Ev; e += 1024){
        int sn = ei[e], d = ei[Ev + e];
        int pos = atomicAdd(&scur[d], 1);
        csrc[pos] = sn;
        cw[pos] = sdv[sn]*ew[e]*sdv[d];
    }
}

// ---- x (bt,n,c) fp32 -> X2b (n, bt*64+c) bf16; tail blocks do weight prep ----
__global__ __launch_bounds__(256) void k_xpose(const float* __restrict__ x,
        short* __restrict__ X2b, const float* __restrict__ W,
        const float* __restrict__ Wg, const float* __restrict__ Wr,
        short* __restrict__ W2, short* __restrict__ Wgt, short* __restrict__ Wrt){
    int bid = blockIdx.x;
    if (bid < ROWS/16){
        int gid = bid*256 + threadIdx.x;     // one float4; total ROWS*16
        int row = gid >> 4, c4 = gid & 15;
        int bt = row / Nv;
        int n  = row - bt*Nv;
        float4 v = ((const float4*)x)[gid];
        short4 sv;
        sv.x = f2bs(v.x); sv.y = f2bs(v.y); sv.z = f2bs(v.z); sv.w = f2bs(v.w);
        *(short4*)(X2b + (size_t)n*(BT*64) + bt*64 + c4*4) = sv;
    } else {
        int idx = (bid - ROWS/16)*256 + threadIdx.x;
        if (idx < Hv*Hv*Kv){
            int o = idx/(Hv*Kv);
            int rem = idx - o*(Hv*Kv);
            int i = rem/Kv, k = rem - i*Kv;
            W2[o*KK + k*Hv + i] = f2bs(W[idx]);           // W2[o][k*128+i]
        } else if (idx < Hv*Hv*Kv + Hv*64){
            int j = idx - Hv*Hv*Kv;
            int o = j >> 6, k = j & 63;
            Wgt[j] = f2bs(Wg[k*Hv + o]);                  // Wgt[o][k]
        } else if (idx < Hv*Hv*Kv + 2*Hv*64){
            int j = idx - Hv*Hv*Kv - Hv*64;
            int o = j >> 6, k = j & 63;
            Wrt[j] = f2bs(Wr[k*Hv + o]);                  // Wrt[o][k]
        }
    }
}

// ---- dense-row SpMM: AGG2[n, btc] = dv^2*X2b[n] + sum_e w_e * X2b[src_e] ----
__global__ __launch_bounds__(256) void k_spmm(const short* __restrict__ X2b,
        const float* __restrict__ dinv, const int* __restrict__ offs,
        const int* __restrict__ csrc, const float* __restrict__ cw,
        short* __restrict__ AGG2){
    int bid = blockIdx.x;
    int ct = bid / Nv;
    int n  = bid - ct*Nv;
    int col = ct*2048 + threadIdx.x*8;
    float dv = dinv[n];
    float sw = dv*dv;
    float acc[8];
    s8v v = *(const s8v*)(X2b + (size_t)n*(BT*64) + col);
    #pragma unroll
    for (int q = 0; q < 8; ++q) acc[q] = sw * b2f(v[q]);
    int e0 = offs[n], e1 = offs[n+1];
    for (int e = e0; e < e1; ++e){
        int s = csrc[e]; float w = cw[e];
        s8v u = *(const s8v*)(X2b + (size_t)s*(BT*64) + col);
        #pragma unroll
        for (int q = 0; q < 8; ++q) acc[q] = fmaf(w, b2f(u[q]), acc[q]);
    }
    s8v r;
    #pragma unroll
    for (int q = 0; q < 8; ++q) r[q] = f2bs(acc[q]);
    *(s8v*)(AGG2 + (size_t)n*(BT*64) + col) = r;
}

// ---- mega kernel: GCN GEMM (K=64) -> GELU -> LDS; residual GEMM (K=64);
//      temporal conv GEMM (K=384); bias+GELU+residual+LayerNorm -> out ----
// block = 4 waves, 4 nodes; wave w owns output channels [w*32, w*32+32).
__global__ __launch_bounds__(256, 2) void k_mega(
        const short* __restrict__ AGG2, const short* __restrict__ X2b,
        const short* __restrict__ W2, const short* __restrict__ Wgt,
        const short* __restrict__ Wrt,
        const float* __restrict__ bg, const float* __restrict__ btm,
        const float* __restrict__ br, const float* __restrict__ lw,
        const float* __restrict__ lb, float* __restrict__ out){
    __shared__ short hs[4*TP*LDSROW];      // 39168 B
    __shared__ float red[Tv][4][2];
    int tid  = threadIdx.x;
    int w    = tid >> 6;
    int lane = tid & 63;
    int quad = lane >> 4;
    int laneo = lane & 15;
    int bid = blockIdx.x;
    int b  = bid / 125;
    int n0 = (bid - b*125) * 4;
    int o_base = w*32;

    float bgv[2], bbv[2], brv[2], lwv[2], lbv[2];
    #pragma unroll
    for (int nt = 0; nt < 2; ++nt){
        int o = o_base + nt*16 + laneo;
        bgv[nt] = bg[o]; bbv[nt] = btm[o]; brv[nt] = br[o];
        lwv[nt] = lw[o]; lbv[nt] = lb[o];
    }

    // GCN B fragments (K=64: 2 k-steps)
    s8v bwg[2][2];
    #pragma unroll
    for (int nt = 0; nt < 2; ++nt){
        const short* wp = Wgt + (o_base + nt*16 + laneo)*64 + quad*8;
        bwg[nt][0] = *(const s8v*)wp;
        bwg[nt][1] = *(const s8v*)(wp + 32);
    }

    // zero the pad rows (tp=0, tp=33) of all 4 nodes
    if (tid < 128){
        int node = tid >> 5, rem = tid & 31;
        int tp = (rem >> 4)*(TP-1), c8 = rem & 15;
        s8v z = {0,0,0,0,0,0,0,0};
        *(s8v*)&hs[node*(TP*LDSROW) + tp*LDSROW + c8*8] = z;
    }

    // ---- stage: GCN GEMM per node, GELU, write h to LDS (A-layout rows) ----
    for (int g = 0; g < 4; ++g){
        int n = n0 + g;
        const short* ap = AGG2 + ((size_t)n*BT + b*Tv)*64;
        #pragma unroll
        for (int m = 0; m < 2; ++m){
            const short* arp = ap + (m*16 + laneo)*64 + quad*8;
            s8v a0 = *(const s8v*)arp;
            s8v a1 = *(const s8v*)(arp + 32);
            f4v h0 = {0.f,0.f,0.f,0.f}, h1 = {0.f,0.f,0.f,0.f};
            h0 = __builtin_amdgcn_mfma_f32_16x16x32_bf16(a0, bwg[0][0], h0, 0,0,0);
            h0 = __builtin_amdgcn_mfma_f32_16x16x32_bf16(a1, bwg[0][1], h0, 0,0,0);
            h1 = __builtin_amdgcn_mfma_f32_16x16x32_bf16(a0, bwg[1][0], h1, 0,0,0);
            h1 = __builtin_amdgcn_mfma_f32_16x16x32_bf16(a1, bwg[1][1], h1, 0,0,0);
            #pragma unroll
            for (int r = 0; r < 4; ++r){
                int tp = m*16 + quad*4 + r + 1;     // C layout: row=quad*4+r
                short* hrow = &hs[g*(TP*LDSROW) + tp*LDSROW];
                hrow[o_base + laneo]      = f2bs(gelu_exact(h0[r] + bgv[0]));
                hrow[o_base + 16 + laneo] = f2bs(gelu_exact(h1[r] + bgv[1]));
            }
        }
    }

    // conv + residual B fragments (loaded late to cut peak VGPR in stage phase)
    s8v breg[2][12], bwr[2][2];
    #pragma unroll
    for (int nt = 0; nt < 2; ++nt){
        int o = o_base + nt*16 + laneo;
        const short* wp = W2 + o*KK + quad*8;
        #pragma unroll
        for (int s = 0; s < 12; ++s)
            breg[nt][s] = *(const s8v*)(wp + s*32);
        const short* wr = Wrt + o*64 + quad*8;
        bwr[nt][0] = *(const s8v*)wr;
        bwr[nt][1] = *(const s8v*)(wr + 32);
    }
    __syncthreads();

    for (int g = 0; g < 4; ++g){
        int n = n0 + g;
        // ---- temporal conv MFMA: 2 m-tiles x 12 K-steps x 2 n-tiles ----
        f4v acc[2][2];
        #pragma unroll
        for (int m = 0; m < 2; ++m)
            #pragma unroll
            for (int nt = 0; nt < 2; ++nt)
                acc[m][nt] = (f4v){0.f,0.f,0.f,0.f};
        #pragma unroll
        for (int m = 0; m < 2; ++m){
            #pragma unroll
            for (int s = 0; s < 12; ++s){
                int k  = s >> 2;
                int i0 = (s & 3) * 32;
                int tp = m*16 + laneo + k;
                s8v a = *(const s8v*)&hs[g*(TP*LDSROW) + tp*LDSROW + i0 + quad*8];
                acc[m][0] = __builtin_amdgcn_mfma_f32_16x16x32_bf16(a, breg[0][s], acc[m][0], 0,0,0);
                acc[m][1] = __builtin_amdgcn_mfma_f32_16x16x32_bf16(a, breg[1][s], acc[m][1], 0,0,0);
            }
        }
        // ---- residual GEMM from X2b window (same C layout -> register add) ----
        f4v racc[2][2];
        #pragma unroll
        for (int m = 0; m < 2; ++m)
            #pragma unroll
            for (int nt = 0; nt < 2; ++nt)
                racc[m][nt] = (f4v){0.f,0.f,0.f,0.f};
        const short* xp = X2b + ((size_t)n*BT + b*Tv)*64;
        #pragma unroll
        for (int m = 0; m < 2; ++m){
            const short* xrp = xp + (m*16 + laneo)*64 + quad*8;
            s8v a0 = *(const s8v*)xrp;
            s8v a1 = *(const s8v*)(xrp + 32);
            racc[m][0] = __builtin_amdgcn_mfma_f32_16x16x32_bf16(a0, bwr[0][0], racc[m][0], 0,0,0);
            racc[m][0] = __builtin_amdgcn_mfma_f32_16x16x32_bf16(a1, bwr[0][1], racc[m][0], 0,0,0);
            racc[m][1] = __builtin_amdgcn_mfma_f32_16x16x32_bf16(a0, bwr[1][0], racc[m][1], 0,0,0);
            racc[m][1] = __builtin_amdgcn_mfma_f32_16x16x32_bf16(a1, bwr[1][1], racc[m][1], 0,0,0);
        }
        // ---- epilogue: bias+GELU+residual, LN stats ----
        size_t obase = ((size_t)b*Tv*Nv + n)*Hv;
        float yv[2][2][4];
        float srow[2][4], ssrow[2][4];
        #pragma unroll
        for (int m = 0; m < 2; ++m)
            #pragma unroll
            for (int r = 0; r < 4; ++r){ srow[m][r] = 0.f; ssrow[m][r] = 0.f; }
        #pragma unroll
        for (int m = 0; m < 2; ++m){
            #pragma unroll
            for (int nt = 0; nt < 2; ++nt){
                #pragma unroll
                for (int r = 0; r < 4; ++r){
                    float gv = gelu_exact(acc[m][nt][r] + bbv[nt]);
                    float y = gv + racc[m][nt][r] + brv[nt];
                    yv[m][nt][r] = y;
                    srow[m][r] += y; ssrow[m][r] += y*y;
                }
            }
        }
        #pragma unroll
        for (int m = 0; m < 2; ++m)
            #pragma unroll
            for (int r = 0; r < 4; ++r){
                #pragma unroll
                for (int msk = 8; msk >= 1; msk >>= 1){
                    srow[m][r]  += __shfl_xor(srow[m][r],  msk, 64);
                    ssrow[m][r] += __shfl_xor(ssrow[m][r], msk, 64);
                }
            }
        if (laneo == 0){
            #pragma unroll
            for (int m = 0; m < 2; ++m)
                #pragma unroll
                for (int r = 0; r < 4; ++r){
                    int t = m*16 + quad*4 + r;
                    red[t][w][0] = srow[m][r];
                    red[t][w][1] = ssrow[m][r];
                }
        }
        __syncthreads();
        #pragma unroll
        for (int m = 0; m < 2; ++m){
            #pragma unroll
            for (int r = 0; r < 4; ++r){
                int t = m*16 + quad*4 + r;
                float s  = red[t][0][0] + red[t][1][0] + red[t][2][0] + red[t][3][0];
                float ss = red[t][0][1] + red[t][1][1] + red[t][2][1] + red[t][3][1];
                float mu = s * (1.f/128.f);
                float var = fmaxf(ss * (1.f/128.f) - mu*mu, 0.f);
                float rstd = rsqrtf(var + 1e-5f);
                #pragma unroll
                for (int nt = 0; nt < 2; ++nt){
                    int o = o_base + nt*16 + laneo;
                    out[obase + (size_t)t*Nv*Hv + o] =
                        (yv[m][nt][r] - mu)*rstd*lwv[nt] + lbv[nt];
                }
            }
        }
        __syncthreads();
    }
}

extern "C" void kernel_launch(void* const* d_in, const int* in_sizes, int n_in,
                              void* d_out, int out_size, void* d_ws, size_t ws_size,
                              hipStream_t stream){
    const float* x   = (const float*)d_in[0];
    const int*   ei  = (const int*)d_in[1];
    const float* ew  = (const float*)d_in[2];
    const float* Wg  = (const float*)d_in[3];
    const float* bg  = (const float*)d_in[4];
    const float* Wtm = (const float*)d_in[5];
    const float* btm = (const float*)d_in[6];
    const float* lw  = (const float*)d_in[7];
    const float* lb  = (const float*)d_in[8];
    const float* Wr  = (const float*)d_in[9];
    const float* br  = (const float*)d_in[10];
    float* out = (float*)d_out;

    char* ws = (char*)d_ws;
    float* dinv = (float*)(ws + 0);            // 2048 B
    int*   offs = (int*)  (ws + 4096);         // 2048 B
    int*   csrc = (int*)  (ws + 8192);         // 32768 B
    float* cwn  = (float*)(ws + 40960);        // 32768 B
    short* W2   = (short*)(ws + 73728);        // 98304 B
    short* Wgt  = (short*)(ws + 172032);       // 16384 B
    short* Wrt  = (short*)(ws + 188416);       // 16384 B
    short* X2b  = (short*)(ws + 204800);       // 16.384 MB
    short* AGG2 = (short*)(ws + 16588800);     // 16.384 MB

    k_prep <<<1, 1024, 0, stream>>>(ei, ew, dinv, offs, csrc, cwn);
    k_xpose<<<ROWS/16 + 256, 256, 0, stream>>>(x, X2b, Wtm, Wg, Wr, W2, Wgt, Wrt);
    k_spmm <<<8*Nv, 256, 0, stream>>>(X2b, dinv, offs, csrc, cwn, AGG2);
    k_mega <<<(Bv*Nv)/4, 256, 0, stream>>>(AGG2, X2b, W2, Wgt, Wrt,
                                           bg, btm, br, lw, lb, out);
}